// Round 17
// baseline (35.467 us; speedup 1.0000x reference)
//
#include <hip/hip_runtime.h>

// QuantumVelocityField: fused 4->128->128->6 silu MLP (fp16 MFMA, fp32 accum)
// + 3-layer RY/RZ single-qubit sim. B = 262144.
//
// R17 vs R16 (remove-work law): consolidate the two half-wave circuit/store
// phases into ONE full-wave phase. 4 passes write params into a 768B/wave
// strip (64 rows x 3 dwords); a single circuit phase runs all 64 lanes
// (lane = row); a single store phase writes 192 contiguous floats/wave.
// Deletes ~half the circuit instrs, 1 of 4 fences, one store prologue.
// LDS 46080B (2 blocks/CU, = grid residency). Everything else = R16.

typedef _Float16 half8 __attribute__((ext_vector_type(8)));
typedef _Float16 half2 __attribute__((ext_vector_type(2)));
typedef float f32x4 __attribute__((ext_vector_type(4)));
typedef float f32x2 __attribute__((ext_vector_type(2)));

#define NBLOCKS 512           // 512 blocks * 8 waves * 64 rows = 262144
#define C2E  1.4426950408889634f            // log2(e)
#define R2PI 0.15915494309189535f           // 1/(2*pi)

union Half8U { half8 v; half2 h2[4]; };

// x' = log2e * x. h' = x' * rcp(1 + 2^(-x')) = log2e * silu(x).
__device__ __forceinline__ half2 silu2x(float x0, float x1) {
    float e0 = __builtin_amdgcn_exp2f(-x0);
    float e1 = __builtin_amdgcn_exp2f(-x1);
    float s0 = x0 * __builtin_amdgcn_rcpf(1.0f + e0);
    float s1 = x1 * __builtin_amdgcn_rcpf(1.0f + e1);
    return __builtin_bit_cast(half2, __builtin_amdgcn_cvt_pkrtz(s0, s1));
}
__device__ __forceinline__ unsigned int pk16(float x0, float x1) {
    return __builtin_bit_cast(unsigned int, __builtin_amdgcn_cvt_pkrtz(x0, x1));
}

#define DSFENCE() do { asm volatile("s_waitcnt lgkmcnt(0)" ::: "memory"); \
                       __builtin_amdgcn_wave_barrier(); } while (0)

// ---------------------------------------------------------------------------
// LDS image (46080 B):
//   h[0,16384)       W2 frags: f=s*8+nt: h[f*512 + l*8 + j] =
//                    W2[s*32+(j>>2)*16+(l>>4)*4+(j&3)][nt*16+(l&15)]
//   h[16384,17408)   W1 padded, x log2e
//   h[17408,19456)   W3 padded, x 0.5/(2pi*log2e); ln>=6 holes = 0
//   f[9728,9856)     b1 x log2e;  f[9856,9984) b2 x log2e
//   bytes [39936,46080): 8 x 768B per-wave param strips (64 rows x 3 dw)
// ---------------------------------------------------------------------------
__global__ __launch_bounds__(512, 3)
void qvf_kernel(const float* __restrict__ tg, const float* __restrict__ blg,
                const float* __restrict__ W1g, const float* __restrict__ b1g,
                const float* __restrict__ W2g, const float* __restrict__ b2g,
                const float* __restrict__ W3g, const float* __restrict__ b3g,
                float* __restrict__ out) {
    __shared__ __align__(16) unsigned char sRaw[46080];
    _Float16* h = (_Float16*)sRaw;
    float*    f = (float*)sRaw;
    const _Float16* sW2 = (const _Float16*)sRaw;               // 32 frags x 1KB
    const _Float16* sW1 = (const _Float16*)(sRaw + 32768);     // padded, x c
    const _Float16* sW3 = (const _Float16*)(sRaw + 34816);     // padded, scaled
    const float*    sB1 = (const float*)(sRaw + 38912);
    const float*    sB2 = (const float*)(sRaw + 39424);

    const int tid  = threadIdx.x;
    const int w    = tid >> 6;          // 8 waves
    const int lane = tid & 63;
    const int q    = lane >> 4;
    const int ln   = lane & 15;

    // wave w's 768B param strip (64 rows x 3 dwords)
    unsigned int* sPU = (unsigned int*)(sRaw + 39936 + w * 768);
    float*        sPF = (float*)sPU;

    // ---- in-block pack: fragment-major, one ds_write_b128 per fragment ----
    // W2: (frag,l) = 32x64 = 2048 entries in 4 rounds of 512 threads.
    #pragma unroll
    for (int r = 0; r < 4; ++r) {
        int idx = r * 512 + tid;
        int frag = idx >> 6, l = idx & 63;
        int s = frag >> 3, nt = frag & 7;
        int qv = l >> 4, l2 = l & 15;
        int n2 = nt * 16 + l2;
        Half8U u;
        #pragma unroll
        for (int hi = 0; hi < 2; ++hi)
            #pragma unroll
            for (int c = 0; c < 4; ++c) {
                int k = s * 32 + hi * 16 + qv * 4 + c;
                u.v[hi * 4 + c] = (_Float16)W2g[k * 128 + n2];
            }
        *(half8*)&h[frag * 512 + l * 8] = u.v;
    }
    // W1 padded (1024 halfs), x log2e: 2 rounds
    #pragma unroll
    for (int r = 0; r < 2; ++r) {
        int i = r * 512 + tid;
        int j = i & 7, l2 = (i >> 3) & 15, nt = i >> 7;
        h[16384 + i] = (j < 4) ? (_Float16)(C2E * W1g[j * 128 + nt * 16 + l2])
                               : (_Float16)0.f;
    }
    // W3 padded: threads 0..255 -> (s, ln, q), one b128 write (holes = 0)
    if (tid < 256) {
        int s = tid >> 6, l2 = (tid >> 2) & 15, qv = tid & 3;
        Half8U u;
        #pragma unroll
        for (int j = 0; j < 8; ++j) {
            int k = s * 32 + ((j >> 2) << 4) + qv * 4 + (j & 3);
            u.v[j] = (l2 < 6) ? (_Float16)((0.5f * R2PI / C2E) * W3g[k * 6 + l2])
                              : (_Float16)0.f;
        }
        *(half8*)&h[17408 + s * 512 + l2 * 32 + qv * 8] = u.v;
    } else if (tid < 384) {
        f[9728 + (tid - 256)] = C2E * b1g[tid - 256];
    } else {
        f[9856 + (tid - 384)] = C2E * b2g[tid - 384];
    }

    // b3 per-lane regs, x 0.5/(2pi) (half-angle, revolutions)
    float b3c[4];
    #pragma unroll
    for (int r = 0; r < 4; ++r) {
        int n3 = 4 * q + r;
        b3c[r] = (n3 < 6) ? (0.5f * R2PI) * b3g[n3] : 0.0f;
    }

    const int rowb = blockIdx.x * 512 + w * 64;   // this wave's 64 rows

    // ---- prefetch all four passes' inputs (q==0 lanes) ----
    half8 bIn[4] = {{}, {}, {}, {}};
    if (q == 0) {
        #pragma unroll
        for (int p = 0; p < 4; ++p) {
            int m = rowb + p * 16 + ln;
            bIn[p][0] = (_Float16)tg[m];
            bIn[p][1] = (_Float16)blg[3 * m + 0];
            bIn[p][2] = (_Float16)blg[3 * m + 1];
            bIn[p][3] = (_Float16)blg[3 * m + 2];
        }
    }

    __syncthreads();

    // ---- 4 passes of 16 rows; params accumulate in the wave strip ----
    #pragma unroll 2
    for (int p = 0; p < 4; ++p) {
        // layer 1 (x' domain): ungated padded A; C-init = b1' frag
        f32x4 acc1[8];
        #pragma unroll
        for (int nt = 0; nt < 8; ++nt) {
            half8 a1 = *(const half8*)&sW1[nt * 128 + ln * 8];
            f32x4 bb = *(const f32x4*)&sB1[nt * 16 + 4 * q];
            acc1[nt] = __builtin_amdgcn_mfma_f32_16x16x32_f16(a1, bIn[p], bb, 0, 0, 0);
        }

        // epilogue 1: exp2-silu -> layer-2 B frags
        half8 bf2[4];
        #pragma unroll
        for (int s = 0; s < 4; ++s) {
            Half8U u;
            #pragma unroll
            for (int hj = 0; hj < 2; ++hj) {
                int nt = 2 * s + hj;
                u.h2[hj * 2 + 0] = silu2x(acc1[nt][0], acc1[nt][1]);
                u.h2[hj * 2 + 1] = silu2x(acc1[nt][2], acc1[nt][3]);
            }
            bf2[s] = u.v;
        }

        // layer 2: fragment-major A; C-init = b2' at s==0
        f32x4 acc2[8];
        #pragma unroll
        for (int s = 0; s < 4; ++s) {
            #pragma unroll
            for (int nt = 0; nt < 8; ++nt) {
                half8 a2 = *(const half8*)&sW2[(s * 8 + nt) * 512 + lane * 8];
                if (s == 0) {
                    f32x4 bb = *(const f32x4*)&sB2[nt * 16 + 4 * q];
                    acc2[nt] = __builtin_amdgcn_mfma_f32_16x16x32_f16(a2, bf2[0], bb, 0, 0, 0);
                } else {
                    acc2[nt] = __builtin_amdgcn_mfma_f32_16x16x32_f16(a2, bf2[s], acc2[nt], 0, 0, 0);
                }
            }
        }

        // epilogue 2: exp2-silu -> layer-3 B frags
        half8 bf3[4];
        #pragma unroll
        for (int s = 0; s < 4; ++s) {
            Half8U u;
            #pragma unroll
            for (int hj = 0; hj < 2; ++hj) {
                int nt = 2 * s + hj;
                u.h2[hj * 2 + 0] = silu2x(acc2[nt][0], acc2[nt][1]);
                u.h2[hj * 2 + 1] = silu2x(acc2[nt][2], acc2[nt][3]);
            }
            bf3[s] = u.v;
        }

        // layer 3: ungated padded A (x 0.5/(2pi*c)); C-init = b3 regs
        f32x4 acc3 = (f32x4){b3c[0], b3c[1], b3c[2], b3c[3]};
        #pragma unroll
        for (int s = 0; s < 4; ++s) {
            half8 a3 = *(const half8*)&sW3[s * 512 + ln * 32 + q * 8];
            acc3 = __builtin_amdgcn_mfma_f32_16x16x32_f16(a3, bf3[s], acc3, 0, 0, 0);
        }

        // epilogue 3: pack revolution-domain params fp16 -> wave strip
        int row = p * 16 + ln;
        if (q == 0) {
            sPU[row * 3 + 0] = pk16(acc3[0], acc3[1]);  // th1, ph1 (rev)
            sPU[row * 3 + 1] = pk16(acc3[2], acc3[3]);  // th2, ph2
        } else if (q == 1) {
            sPU[row * 3 + 2] = pk16(acc3[0], acc3[1]);  // th3, ph3
        }
    }
    DSFENCE();   // all 64 rows' params visible to all lanes

    // ---- circuit sim: ONE full-wave phase, lane = row ----
    {
        half2 h0 = __builtin_bit_cast(half2, sPU[lane * 3 + 0]);
        half2 h1 = __builtin_bit_cast(half2, sPU[lane * 3 + 1]);
        half2 h2 = __builtin_bit_cast(half2, sPU[lane * 3 + 2]);
        float pr[6] = {(float)h0[0], (float)h0[1], (float)h1[0],
                       (float)h1[1], (float)h2[0], (float)h2[1]};
        float ar = 1.f, ai = 0.f, br = 0.f, bi = 0.f;
        #pragma unroll
        for (int l = 0; l < 3; ++l) {
            float th = pr[2 * l];
            float ph = pr[2 * l + 1];
            float s1 = __builtin_amdgcn_sinf(th), c1 = __builtin_amdgcn_cosf(th);
            float a1r = c1 * ar - s1 * br, a1i = c1 * ai - s1 * bi;
            float b1r = s1 * ar + c1 * br, b1i = s1 * ai + c1 * bi;
            float se = __builtin_amdgcn_sinf(ph), ce = __builtin_amdgcn_cosf(ph);
            ar = ce * a1r + se * a1i; ai = ce * a1i - se * a1r;
            br = ce * b1r - se * b1i; bi = ce * b1i + se * b1r;
        }
        // same-lane same-address: ordered within a lane
        sPF[lane * 3 + 0] = 2.f * (ar * br + ai * bi);
        sPF[lane * 3 + 1] = 2.f * (ar * bi - ai * br);
        sPF[lane * 3 + 2] = ar * ar + ai * ai - br * br - bi * bi;
    }
    DSFENCE();   // results visible cross-lane

    // ---- coalesced stores: 192 contiguous floats per wave ----
    {
        float* ob = &out[3 * rowb];
        f32x2 v0 = *(const f32x2*)&sPF[2 * lane];
        *(f32x2*)&ob[2 * lane] = v0;                  // floats [0,128)
        if (lane < 32) {
            f32x2 v1 = *(const f32x2*)&sPF[128 + 2 * lane];
            *(f32x2*)&ob[128 + 2 * lane] = v1;        // floats [128,192)
        }
    }
}

extern "C" void kernel_launch(void* const* d_in, const int* in_sizes, int n_in,
                              void* d_out, int out_size, void* d_ws, size_t ws_size,
                              hipStream_t stream) {
    const float* t  = (const float*)d_in[0];
    const float* bl = (const float*)d_in[1];
    const float* W1 = (const float*)d_in[2];
    const float* b1 = (const float*)d_in[3];
    const float* W2 = (const float*)d_in[4];
    const float* b2 = (const float*)d_in[5];
    const float* W3 = (const float*)d_in[6];
    const float* b3 = (const float*)d_in[7];
    qvf_kernel<<<NBLOCKS, 512, 0, stream>>>(t, bl, W1, b1, W2, b2, W3, b3, (float*)d_out);
}

// Round 18
// 26.373 us; speedup vs baseline: 1.3448x; 1.3448x over previous
//
#include <hip/hip_runtime.h>

// QuantumVelocityField: fused 4->128->128->6 silu MLP (fp16 MFMA, fp32 accum)
// + 3-layer RY/RZ single-qubit sim. B = 262144.
//
// R18 = R16 reverted (R17's 4-pass consolidation broke the scheduler's
// phase interleave: VALUBusy 67->47%, dur 29.4->35.5). Only delta vs R16:
// the group loop is fully unrolled so bIn indices are compile-time
// literals. Structure: 512 blocks x 8 waves x 64 rows; 2 groups of
// {2x16-row passes -> lane<32 circuit -> store}; exp2-domain silu;
// raw v_sin/v_cos (revolutions); in-block fragment-major pack.

typedef _Float16 half8 __attribute__((ext_vector_type(8)));
typedef _Float16 half2 __attribute__((ext_vector_type(2)));
typedef float f32x4 __attribute__((ext_vector_type(4)));
typedef float f32x2 __attribute__((ext_vector_type(2)));

#define NBLOCKS 512           // 512 blocks * 8 waves * 64 rows = 262144
#define C2E  1.4426950408889634f            // log2(e)
#define R2PI 0.15915494309189535f           // 1/(2*pi)

union Half8U { half8 v; half2 h2[4]; };

// x' = log2e * x. h' = x' * rcp(1 + 2^(-x')) = log2e * silu(x).
__device__ __forceinline__ half2 silu2x(float x0, float x1) {
    float e0 = __builtin_amdgcn_exp2f(-x0);
    float e1 = __builtin_amdgcn_exp2f(-x1);
    float s0 = x0 * __builtin_amdgcn_rcpf(1.0f + e0);
    float s1 = x1 * __builtin_amdgcn_rcpf(1.0f + e1);
    return __builtin_bit_cast(half2, __builtin_amdgcn_cvt_pkrtz(s0, s1));
}
__device__ __forceinline__ unsigned int pk16(float x0, float x1) {
    return __builtin_bit_cast(unsigned int, __builtin_amdgcn_cvt_pkrtz(x0, x1));
}

#define DSFENCE() do { asm volatile("s_waitcnt lgkmcnt(0)" ::: "memory"); \
                       __builtin_amdgcn_wave_barrier(); } while (0)

// ---------------------------------------------------------------------------
// LDS image (43008 B):
//   h[0,16384)       W2 frags: f=s*8+nt: h[f*512 + l*8 + j] =
//                    W2[s*32+(j>>2)*16+(l>>4)*4+(j&3)][nt*16+(l&15)]
//   h[16384,17408)   W1 padded, x log2e
//   h[17408,19456)   W3 padded, x 0.5/(2pi*log2e); ln>=6 holes = 0
//   f[9728,9856)     b1 x log2e;  f[9856,9984) b2 x log2e
//   bytes [39936,43008): 8 x 384B per-wave param strips
// ---------------------------------------------------------------------------
__global__ __launch_bounds__(512, 3)
void qvf_kernel(const float* __restrict__ tg, const float* __restrict__ blg,
                const float* __restrict__ W1g, const float* __restrict__ b1g,
                const float* __restrict__ W2g, const float* __restrict__ b2g,
                const float* __restrict__ W3g, const float* __restrict__ b3g,
                float* __restrict__ out) {
    __shared__ __align__(16) unsigned char sRaw[43008];
    _Float16* h = (_Float16*)sRaw;
    float*    f = (float*)sRaw;
    const _Float16* sW2 = (const _Float16*)sRaw;               // 32 frags x 1KB
    const _Float16* sW1 = (const _Float16*)(sRaw + 32768);     // padded, x c
    const _Float16* sW3 = (const _Float16*)(sRaw + 34816);     // padded, scaled
    const float*    sB1 = (const float*)(sRaw + 38912);
    const float*    sB2 = (const float*)(sRaw + 39424);

    const int tid  = threadIdx.x;
    const int w    = tid >> 6;          // 8 waves
    const int lane = tid & 63;
    const int q    = lane >> 4;
    const int ln   = lane & 15;

    // wave w's 384B param strip (dedicated region)
    unsigned int* sPU = (unsigned int*)(sRaw + 39936 + w * 384);
    float*        sPF = (float*)sPU;

    // ---- in-block pack: fragment-major, one ds_write_b128 per fragment ----
    // W2: (frag,l) = 32x64 = 2048 entries in 4 rounds of 512 threads.
    #pragma unroll
    for (int r = 0; r < 4; ++r) {
        int idx = r * 512 + tid;
        int frag = idx >> 6, l = idx & 63;
        int s = frag >> 3, nt = frag & 7;
        int qv = l >> 4, l2 = l & 15;
        int n2 = nt * 16 + l2;
        Half8U u;
        #pragma unroll
        for (int hi = 0; hi < 2; ++hi)
            #pragma unroll
            for (int c = 0; c < 4; ++c) {
                int k = s * 32 + hi * 16 + qv * 4 + c;
                u.v[hi * 4 + c] = (_Float16)W2g[k * 128 + n2];
            }
        *(half8*)&h[frag * 512 + l * 8] = u.v;
    }
    // W1 padded (1024 halfs), x log2e: 2 rounds
    #pragma unroll
    for (int r = 0; r < 2; ++r) {
        int i = r * 512 + tid;
        int j = i & 7, l2 = (i >> 3) & 15, nt = i >> 7;
        h[16384 + i] = (j < 4) ? (_Float16)(C2E * W1g[j * 128 + nt * 16 + l2])
                               : (_Float16)0.f;
    }
    // W3 padded: threads 0..255 -> (s, ln, q), one b128 write (holes = 0)
    if (tid < 256) {
        int s = tid >> 6, l2 = (tid >> 2) & 15, qv = tid & 3;
        Half8U u;
        #pragma unroll
        for (int j = 0; j < 8; ++j) {
            int k = s * 32 + ((j >> 2) << 4) + qv * 4 + (j & 3);
            u.v[j] = (l2 < 6) ? (_Float16)((0.5f * R2PI / C2E) * W3g[k * 6 + l2])
                              : (_Float16)0.f;
        }
        *(half8*)&h[17408 + s * 512 + l2 * 32 + qv * 8] = u.v;
    } else if (tid < 384) {
        f[9728 + (tid - 256)] = C2E * b1g[tid - 256];
    } else {
        f[9856 + (tid - 384)] = C2E * b2g[tid - 384];
    }

    // b3 per-lane regs, x 0.5/(2pi) (half-angle, revolutions)
    float b3c[4];
    #pragma unroll
    for (int r = 0; r < 4; ++r) {
        int n3 = 4 * q + r;
        b3c[r] = (n3 < 6) ? (0.5f * R2PI) * b3g[n3] : 0.0f;
    }

    const int rowb = blockIdx.x * 512 + w * 64;   // this wave's 64 rows

    // ---- prefetch all four passes' inputs (q==0 lanes) ----
    half8 bIn[4] = {{}, {}, {}, {}};
    if (q == 0) {
        #pragma unroll
        for (int p = 0; p < 4; ++p) {
            int m = rowb + p * 16 + ln;
            bIn[p][0] = (_Float16)tg[m];
            bIn[p][1] = (_Float16)blg[3 * m + 0];
            bIn[p][2] = (_Float16)blg[3 * m + 1];
            bIn[p][3] = (_Float16)blg[3 * m + 2];
        }
    }

    __syncthreads();

    // ---- 2 groups x 2 passes of 16 rows; circuit + store per group ----
    #pragma unroll
    for (int g = 0; g < 2; ++g) {
        #pragma unroll
        for (int p = 0; p < 2; ++p) {
            const int gp = g * 2 + p;
            // layer 1 (x' domain): ungated padded A; C-init = b1' frag
            f32x4 acc1[8];
            #pragma unroll
            for (int nt = 0; nt < 8; ++nt) {
                half8 a1 = *(const half8*)&sW1[nt * 128 + ln * 8];
                f32x4 bb = *(const f32x4*)&sB1[nt * 16 + 4 * q];
                acc1[nt] = __builtin_amdgcn_mfma_f32_16x16x32_f16(a1, bIn[gp], bb, 0, 0, 0);
            }

            // epilogue 1: exp2-silu -> layer-2 B frags
            half8 bf2[4];
            #pragma unroll
            for (int s = 0; s < 4; ++s) {
                Half8U u;
                #pragma unroll
                for (int hj = 0; hj < 2; ++hj) {
                    int nt = 2 * s + hj;
                    u.h2[hj * 2 + 0] = silu2x(acc1[nt][0], acc1[nt][1]);
                    u.h2[hj * 2 + 1] = silu2x(acc1[nt][2], acc1[nt][3]);
                }
                bf2[s] = u.v;
            }

            // layer 2: fragment-major A; C-init = b2' at s==0
            f32x4 acc2[8];
            #pragma unroll
            for (int s = 0; s < 4; ++s) {
                #pragma unroll
                for (int nt = 0; nt < 8; ++nt) {
                    half8 a2 = *(const half8*)&sW2[(s * 8 + nt) * 512 + lane * 8];
                    if (s == 0) {
                        f32x4 bb = *(const f32x4*)&sB2[nt * 16 + 4 * q];
                        acc2[nt] = __builtin_amdgcn_mfma_f32_16x16x32_f16(a2, bf2[0], bb, 0, 0, 0);
                    } else {
                        acc2[nt] = __builtin_amdgcn_mfma_f32_16x16x32_f16(a2, bf2[s], acc2[nt], 0, 0, 0);
                    }
                }
            }

            // epilogue 2: exp2-silu -> layer-3 B frags
            half8 bf3[4];
            #pragma unroll
            for (int s = 0; s < 4; ++s) {
                Half8U u;
                #pragma unroll
                for (int hj = 0; hj < 2; ++hj) {
                    int nt = 2 * s + hj;
                    u.h2[hj * 2 + 0] = silu2x(acc2[nt][0], acc2[nt][1]);
                    u.h2[hj * 2 + 1] = silu2x(acc2[nt][2], acc2[nt][3]);
                }
                bf3[s] = u.v;
            }

            // layer 3: ungated padded A (x 0.5/(2pi*c)); C-init = b3 regs
            f32x4 acc3 = (f32x4){b3c[0], b3c[1], b3c[2], b3c[3]};
            #pragma unroll
            for (int s = 0; s < 4; ++s) {
                half8 a3 = *(const half8*)&sW3[s * 512 + ln * 32 + q * 8];
                acc3 = __builtin_amdgcn_mfma_f32_16x16x32_f16(a3, bf3[s], acc3, 0, 0, 0);
            }

            // epilogue 3: pack revolution-domain params fp16 -> wave strip
            int row = p * 16 + ln;
            if (q == 0) {
                sPU[row * 3 + 0] = pk16(acc3[0], acc3[1]);  // th1, ph1 (rev)
                sPU[row * 3 + 1] = pk16(acc3[2], acc3[3]);  // th2, ph2
            } else if (q == 1) {
                sPU[row * 3 + 2] = pk16(acc3[0], acc3[1]);  // th3, ph3
            }
        }
        DSFENCE();   // params visible to all lanes

        // ---- circuit sim: lanes 0..31, raw v_sin/v_cos (revolutions) ----
        if (lane < 32) {
            half2 h0 = __builtin_bit_cast(half2, sPU[lane * 3 + 0]);
            half2 h1 = __builtin_bit_cast(half2, sPU[lane * 3 + 1]);
            half2 h2 = __builtin_bit_cast(half2, sPU[lane * 3 + 2]);
            float pr[6] = {(float)h0[0], (float)h0[1], (float)h1[0],
                           (float)h1[1], (float)h2[0], (float)h2[1]};
            float ar = 1.f, ai = 0.f, br = 0.f, bi = 0.f;
            #pragma unroll
            for (int l = 0; l < 3; ++l) {
                float th = pr[2 * l];
                float ph = pr[2 * l + 1];
                float s1 = __builtin_amdgcn_sinf(th), c1 = __builtin_amdgcn_cosf(th);
                float a1r = c1 * ar - s1 * br, a1i = c1 * ai - s1 * bi;
                float b1r = s1 * ar + c1 * br, b1i = s1 * ai + c1 * bi;
                float se = __builtin_amdgcn_sinf(ph), ce = __builtin_amdgcn_cosf(ph);
                ar = ce * a1r + se * a1i; ai = ce * a1i - se * a1r;
                br = ce * b1r - se * b1i; bi = ce * b1i + se * b1r;
            }
            // same-lane same-address: ordered within a lane
            sPF[lane * 3 + 0] = 2.f * (ar * br + ai * bi);
            sPF[lane * 3 + 1] = 2.f * (ar * bi - ai * br);
            sPF[lane * 3 + 2] = ar * ar + ai * ai - br * br - bi * bi;
        }
        DSFENCE();   // results visible cross-lane

        // ---- coalesced stores: 96 floats per group, 48-lane dwordx2 ----
        if (lane < 48) {
            f32x2 vv = *(const f32x2*)&sPF[2 * lane];
            *(f32x2*)&out[3 * (rowb + g * 32) + 2 * lane] = vv;
        }
        DSFENCE();   // strip reads complete before next group's param writes
    }
}

extern "C" void kernel_launch(void* const* d_in, const int* in_sizes, int n_in,
                              void* d_out, int out_size, void* d_ws, size_t ws_size,
                              hipStream_t stream) {
    const float* t  = (const float*)d_in[0];
    const float* bl = (const float*)d_in[1];
    const float* W1 = (const float*)d_in[2];
    const float* b1 = (const float*)d_in[3];
    const float* W2 = (const float*)d_in[4];
    const float* b2 = (const float*)d_in[5];
    const float* W3 = (const float*)d_in[6];
    const float* b3 = (const float*)d_in[7];
    qvf_kernel<<<NBLOCKS, 512, 0, stream>>>(t, bl, W1, b1, W2, b2, W3, b3, (float*)d_out);
}

// Round 19
// 25.773 us; speedup vs baseline: 1.3762x; 1.0233x over previous
//
#include <hip/hip_runtime.h>

// QuantumVelocityField: fused 4->128->128->6 silu MLP (fp16 MFMA, fp32 accum)
// + 3-layer RY/RZ single-qubit sim. B = 262144.
//
// R19 = R18 with 256 blocks x 1024 threads (16 waves): staging executed
// ONCE per CU (was twice) by 2x threads. A/B: staging-amortization vs lost
// inter-block staging/compute overlap. __launch_bounds__(1024,4) (cap 128;
// R10-proven ~120-reg pipeline fits). LDS 46080B (16 x 384B strips).
// Everything else identical to R18 (2 groups, per-group circuit+store,
// exp2-silu, raw sin/cos revolutions, fragment-major in-block pack).

typedef _Float16 half8 __attribute__((ext_vector_type(8)));
typedef _Float16 half2 __attribute__((ext_vector_type(2)));
typedef float f32x4 __attribute__((ext_vector_type(4)));
typedef float f32x2 __attribute__((ext_vector_type(2)));

#define NBLOCKS 256           // 256 blocks * 16 waves * 64 rows = 262144
#define C2E  1.4426950408889634f            // log2(e)
#define R2PI 0.15915494309189535f           // 1/(2*pi)

union Half8U { half8 v; half2 h2[4]; };

// x' = log2e * x. h' = x' * rcp(1 + 2^(-x')) = log2e * silu(x).
__device__ __forceinline__ half2 silu2x(float x0, float x1) {
    float e0 = __builtin_amdgcn_exp2f(-x0);
    float e1 = __builtin_amdgcn_exp2f(-x1);
    float s0 = x0 * __builtin_amdgcn_rcpf(1.0f + e0);
    float s1 = x1 * __builtin_amdgcn_rcpf(1.0f + e1);
    return __builtin_bit_cast(half2, __builtin_amdgcn_cvt_pkrtz(s0, s1));
}
__device__ __forceinline__ unsigned int pk16(float x0, float x1) {
    return __builtin_bit_cast(unsigned int, __builtin_amdgcn_cvt_pkrtz(x0, x1));
}

#define DSFENCE() do { asm volatile("s_waitcnt lgkmcnt(0)" ::: "memory"); \
                       __builtin_amdgcn_wave_barrier(); } while (0)

// ---------------------------------------------------------------------------
// LDS image (46080 B):
//   h[0,16384)       W2 frags: f=s*8+nt: h[f*512 + l*8 + j] =
//                    W2[s*32+(j>>2)*16+(l>>4)*4+(j&3)][nt*16+(l&15)]
//   h[16384,17408)   W1 padded, x log2e
//   h[17408,19456)   W3 padded, x 0.5/(2pi*log2e); ln>=6 holes = 0
//   f[9728,9856)     b1 x log2e;  f[9856,9984) b2 x log2e
//   bytes [39936,46080): 16 x 384B per-wave param strips
// ---------------------------------------------------------------------------
__global__ __launch_bounds__(1024, 4)
void qvf_kernel(const float* __restrict__ tg, const float* __restrict__ blg,
                const float* __restrict__ W1g, const float* __restrict__ b1g,
                const float* __restrict__ W2g, const float* __restrict__ b2g,
                const float* __restrict__ W3g, const float* __restrict__ b3g,
                float* __restrict__ out) {
    __shared__ __align__(16) unsigned char sRaw[46080];
    _Float16* h = (_Float16*)sRaw;
    float*    f = (float*)sRaw;
    const _Float16* sW2 = (const _Float16*)sRaw;               // 32 frags x 1KB
    const _Float16* sW1 = (const _Float16*)(sRaw + 32768);     // padded, x c
    const _Float16* sW3 = (const _Float16*)(sRaw + 34816);     // padded, scaled
    const float*    sB1 = (const float*)(sRaw + 38912);
    const float*    sB2 = (const float*)(sRaw + 39424);

    const int tid  = threadIdx.x;
    const int w    = tid >> 6;          // 16 waves
    const int lane = tid & 63;
    const int q    = lane >> 4;
    const int ln   = lane & 15;

    // wave w's 384B param strip (dedicated region)
    unsigned int* sPU = (unsigned int*)(sRaw + 39936 + w * 384);
    float*        sPF = (float*)sPU;

    // ---- in-block pack: fragment-major, one ds_write_b128 per fragment ----
    // W2: (frag,l) = 32x64 = 2048 entries in 2 rounds of 1024 threads.
    #pragma unroll
    for (int r = 0; r < 2; ++r) {
        int idx = r * 1024 + tid;
        int frag = idx >> 6, l = idx & 63;
        int s = frag >> 3, nt = frag & 7;
        int qv = l >> 4, l2 = l & 15;
        int n2 = nt * 16 + l2;
        Half8U u;
        #pragma unroll
        for (int hi = 0; hi < 2; ++hi)
            #pragma unroll
            for (int c = 0; c < 4; ++c) {
                int k = s * 32 + hi * 16 + qv * 4 + c;
                u.v[hi * 4 + c] = (_Float16)W2g[k * 128 + n2];
            }
        *(half8*)&h[frag * 512 + l * 8] = u.v;
    }
    // W1 padded (1024 halfs), x log2e: 1 round
    {
        int i = tid;
        int j = i & 7, l2 = (i >> 3) & 15, nt = i >> 7;
        h[16384 + i] = (j < 4) ? (_Float16)(C2E * W1g[j * 128 + nt * 16 + l2])
                               : (_Float16)0.f;
    }
    // W3 padded: threads 0..255 -> (s, ln, q), one b128 write (holes = 0)
    if (tid < 256) {
        int s = tid >> 6, l2 = (tid >> 2) & 15, qv = tid & 3;
        Half8U u;
        #pragma unroll
        for (int j = 0; j < 8; ++j) {
            int k = s * 32 + ((j >> 2) << 4) + qv * 4 + (j & 3);
            u.v[j] = (l2 < 6) ? (_Float16)((0.5f * R2PI / C2E) * W3g[k * 6 + l2])
                              : (_Float16)0.f;
        }
        *(half8*)&h[17408 + s * 512 + l2 * 32 + qv * 8] = u.v;
    } else if (tid < 384) {
        f[9728 + (tid - 256)] = C2E * b1g[tid - 256];
    } else if (tid < 512) {
        f[9856 + (tid - 384)] = C2E * b2g[tid - 384];
    }

    // b3 per-lane regs, x 0.5/(2pi) (half-angle, revolutions)
    float b3c[4];
    #pragma unroll
    for (int r = 0; r < 4; ++r) {
        int n3 = 4 * q + r;
        b3c[r] = (n3 < 6) ? (0.5f * R2PI) * b3g[n3] : 0.0f;
    }

    const int rowb = blockIdx.x * 1024 + w * 64;   // this wave's 64 rows

    // ---- prefetch all four passes' inputs (q==0 lanes) ----
    half8 bIn[4] = {{}, {}, {}, {}};
    if (q == 0) {
        #pragma unroll
        for (int p = 0; p < 4; ++p) {
            int m = rowb + p * 16 + ln;
            bIn[p][0] = (_Float16)tg[m];
            bIn[p][1] = (_Float16)blg[3 * m + 0];
            bIn[p][2] = (_Float16)blg[3 * m + 1];
            bIn[p][3] = (_Float16)blg[3 * m + 2];
        }
    }

    __syncthreads();

    // ---- 2 groups x 2 passes of 16 rows; circuit + store per group ----
    #pragma unroll
    for (int g = 0; g < 2; ++g) {
        #pragma unroll
        for (int p = 0; p < 2; ++p) {
            const int gp = g * 2 + p;
            // layer 1 (x' domain): ungated padded A; C-init = b1' frag
            f32x4 acc1[8];
            #pragma unroll
            for (int nt = 0; nt < 8; ++nt) {
                half8 a1 = *(const half8*)&sW1[nt * 128 + ln * 8];
                f32x4 bb = *(const f32x4*)&sB1[nt * 16 + 4 * q];
                acc1[nt] = __builtin_amdgcn_mfma_f32_16x16x32_f16(a1, bIn[gp], bb, 0, 0, 0);
            }

            // epilogue 1: exp2-silu -> layer-2 B frags
            half8 bf2[4];
            #pragma unroll
            for (int s = 0; s < 4; ++s) {
                Half8U u;
                #pragma unroll
                for (int hj = 0; hj < 2; ++hj) {
                    int nt = 2 * s + hj;
                    u.h2[hj * 2 + 0] = silu2x(acc1[nt][0], acc1[nt][1]);
                    u.h2[hj * 2 + 1] = silu2x(acc1[nt][2], acc1[nt][3]);
                }
                bf2[s] = u.v;
            }

            // layer 2: fragment-major A; C-init = b2' at s==0
            f32x4 acc2[8];
            #pragma unroll
            for (int s = 0; s < 4; ++s) {
                #pragma unroll
                for (int nt = 0; nt < 8; ++nt) {
                    half8 a2 = *(const half8*)&sW2[(s * 8 + nt) * 512 + lane * 8];
                    if (s == 0) {
                        f32x4 bb = *(const f32x4*)&sB2[nt * 16 + 4 * q];
                        acc2[nt] = __builtin_amdgcn_mfma_f32_16x16x32_f16(a2, bf2[0], bb, 0, 0, 0);
                    } else {
                        acc2[nt] = __builtin_amdgcn_mfma_f32_16x16x32_f16(a2, bf2[s], acc2[nt], 0, 0, 0);
                    }
                }
            }

            // epilogue 2: exp2-silu -> layer-3 B frags
            half8 bf3[4];
            #pragma unroll
            for (int s = 0; s < 4; ++s) {
                Half8U u;
                #pragma unroll
                for (int hj = 0; hj < 2; ++hj) {
                    int nt = 2 * s + hj;
                    u.h2[hj * 2 + 0] = silu2x(acc2[nt][0], acc2[nt][1]);
                    u.h2[hj * 2 + 1] = silu2x(acc2[nt][2], acc2[nt][3]);
                }
                bf3[s] = u.v;
            }

            // layer 3: ungated padded A (x 0.5/(2pi*c)); C-init = b3 regs
            f32x4 acc3 = (f32x4){b3c[0], b3c[1], b3c[2], b3c[3]};
            #pragma unroll
            for (int s = 0; s < 4; ++s) {
                half8 a3 = *(const half8*)&sW3[s * 512 + ln * 32 + q * 8];
                acc3 = __builtin_amdgcn_mfma_f32_16x16x32_f16(a3, bf3[s], acc3, 0, 0, 0);
            }

            // epilogue 3: pack revolution-domain params fp16 -> wave strip
            int row = p * 16 + ln;
            if (q == 0) {
                sPU[row * 3 + 0] = pk16(acc3[0], acc3[1]);  // th1, ph1 (rev)
                sPU[row * 3 + 1] = pk16(acc3[2], acc3[3]);  // th2, ph2
            } else if (q == 1) {
                sPU[row * 3 + 2] = pk16(acc3[0], acc3[1]);  // th3, ph3
            }
        }
        DSFENCE();   // params visible to all lanes

        // ---- circuit sim: lanes 0..31, raw v_sin/v_cos (revolutions) ----
        if (lane < 32) {
            half2 h0 = __builtin_bit_cast(half2, sPU[lane * 3 + 0]);
            half2 h1 = __builtin_bit_cast(half2, sPU[lane * 3 + 1]);
            half2 h2 = __builtin_bit_cast(half2, sPU[lane * 3 + 2]);
            float pr[6] = {(float)h0[0], (float)h0[1], (float)h1[0],
                           (float)h1[1], (float)h2[0], (float)h2[1]};
            float ar = 1.f, ai = 0.f, br = 0.f, bi = 0.f;
            #pragma unroll
            for (int l = 0; l < 3; ++l) {
                float th = pr[2 * l];
                float ph = pr[2 * l + 1];
                float s1 = __builtin_amdgcn_sinf(th), c1 = __builtin_amdgcn_cosf(th);
                float a1r = c1 * ar - s1 * br, a1i = c1 * ai - s1 * bi;
                float b1r = s1 * ar + c1 * br, b1i = s1 * ai + c1 * bi;
                float se = __builtin_amdgcn_sinf(ph), ce = __builtin_amdgcn_cosf(ph);
                ar = ce * a1r + se * a1i; ai = ce * a1i - se * a1r;
                br = ce * b1r - se * b1i; bi = ce * b1i + se * b1r;
            }
            // same-lane same-address: ordered within a lane
            sPF[lane * 3 + 0] = 2.f * (ar * br + ai * bi);
            sPF[lane * 3 + 1] = 2.f * (ar * bi - ai * br);
            sPF[lane * 3 + 2] = ar * ar + ai * ai - br * br - bi * bi;
        }
        DSFENCE();   // results visible cross-lane

        // ---- coalesced stores: 96 floats per group, 48-lane dwordx2 ----
        if (lane < 48) {
            f32x2 vv = *(const f32x2*)&sPF[2 * lane];
            *(f32x2*)&out[3 * (rowb + g * 32) + 2 * lane] = vv;
        }
        DSFENCE();   // strip reads complete before next group's param writes
    }
}

extern "C" void kernel_launch(void* const* d_in, const int* in_sizes, int n_in,
                              void* d_out, int out_size, void* d_ws, size_t ws_size,
                              hipStream_t stream) {
    const float* t  = (const float*)d_in[0];
    const float* bl = (const float*)d_in[1];
    const float* W1 = (const float*)d_in[2];
    const float* b1 = (const float*)d_in[3];
    const float* W2 = (const float*)d_in[4];
    const float* b2 = (const float*)d_in[5];
    const float* W3 = (const float*)d_in[6];
    const float* b3 = (const float*)d_in[7];
    qvf_kernel<<<NBLOCKS, 1024, 0, stream>>>(t, bl, W1, b1, W2, b2, W3, b3, (float*)d_out);
}